// Round 2
// baseline (83.501 us; speedup 1.0000x reference)
//
#include <hip/hip_runtime.h>
#include <hip/hip_bf16.h>
#include <math.h>

typedef __attribute__((ext_vector_type(8))) short short8;
typedef __attribute__((ext_vector_type(4))) float f32x4;

#define NB 8192
#define ND 256
#define RT 64                      // rows per block (denom kernel)
#define CS 4                       // column splits
#define COLS_PER_SPLIT (NB / CS)   // 2048
#define CT 64                      // columns per iteration
#define NITER (COLS_PER_SPLIT / CT)
#define LN2f 0.6931471805599453f

__device__ __forceinline__ float bf2f(ushort u) {
  unsigned int x = ((unsigned int)u) << 16;
  return __builtin_bit_cast(float, x);
}
__device__ __forceinline__ ushort f2bf(float x) {
  return __builtin_bit_cast(ushort, __float2bfloat16(x));
}
__device__ __forceinline__ int swz(int row) {
  return (row & 7) | ((row & 8) << 1);   // 4-bit row entropy -> 5-bit slot mask
}

// ------- row normalize, fold 1/sqrt(T*ln2), quantize bf16, exact self d_r ----
__global__ void norm_kernel(const float* __restrict__ h, ushort* __restrict__ hs,
                            float* __restrict__ dbuf) {
  const float SCALE = 1.0f / sqrtf(0.07f * 0.6931471805599453f);
  int lane = threadIdx.x & 63;
  int wave = threadIdx.x >> 6;
  int row = blockIdx.x * 4 + wave;
  const float4* rp = reinterpret_cast<const float4*>(h + (size_t)row * ND);
  float4 v = rp[lane];
  float ss = v.x * v.x + v.y * v.y + v.z * v.z + v.w * v.w;
#pragma unroll
  for (int d = 1; d <= 32; d <<= 1) ss += __shfl_xor(ss, d);
  float scale = SCALE / fmaxf(sqrtf(ss), 1e-12f);
  ushort4 o;
  o.x = f2bf(v.x * scale);
  o.y = f2bf(v.y * scale);
  o.z = f2bf(v.z * scale);
  o.w = f2bf(v.w * scale);
  reinterpret_cast<ushort4*>(hs + (size_t)row * ND)[lane] = o;
  float qx = bf2f(o.x), qy = bf2f(o.y), qz = bf2f(o.z), qw = bf2f(o.w);
  float dd = qx * qx + qy * qy + qz * qz + qw * qw;   // exact ||q||^2 (log2 units)
#pragma unroll
  for (int d = 1; d <= 32; d <<= 1) dd += __shfl_xor(dd, d);
  if (lane == 0) dbuf[row] = dd;
}

// ------- per-class sums C_l = sum of quantized rows, and member counts -------
__global__ void classsum_kernel(const ushort* __restrict__ hs,
                                const int* __restrict__ labels,
                                float* __restrict__ Cs, float* __restrict__ cnt) {
  __shared__ int list[NB];
  __shared__ int lcnt;
  int c = blockIdx.x, t = threadIdx.x;
  if (t == 0) lcnt = 0;
  __syncthreads();
  for (int i = t; i < NB; i += 256)
    if (labels[i] == c) list[atomicAdd(&lcnt, 1)] = i;
  __syncthreads();
  int n = lcnt;
  float acc = 0.f;
  for (int k = 0; k < n; ++k)
    acc += bf2f(hs[(size_t)list[k] * ND + t]);
  Cs[c * ND + t] = acc;
  if (t == 0) cnt[c] = (float)n;
}

// stage 64 rows x 256 bf16 (32KB): linear LDS dest + inverse-swizzled source
__device__ __forceinline__ void stage64(const ushort* gsrc, ushort* lds,
                                        int wave, int lane) {
#pragma unroll
  for (int c = 0; c < 8; ++c) {
    int u = (wave * 8 + c) * 64 + lane;  // 16B unit, 0..2047
    int row = u >> 5;                    // 32 units per 512B row
    int slot = u & 31;
    int srcslot = slot ^ swz(row);
    const char* g = (const char*)gsrc + row * 512 + srcslot * 16;
    __builtin_amdgcn_global_load_lds(
        (const __attribute__((address_space(1))) unsigned int*)g,
        (__attribute__((address_space(3))) unsigned int*)(lds + (wave * 8 + c) * 512),
        16, 0, 0);
  }
}

// swizzled 16B fragment read; unit = 16B-chunk index within the row (0..31)
__device__ __forceinline__ short8 fload(const ushort* lds, int row, int unit) {
  int slot = unit ^ swz(row);
  return *(const short8*)(lds + row * 256 + slot * 8);
}

// ------- denominator: s_r(split) = sum_j exp2(sim2_rj), no labels, no max ----
__global__ __launch_bounds__(256, 2)
void denom_kernel(const ushort* __restrict__ hs, float* __restrict__ partials) {
  __shared__ ushort Alds[RT * ND];
  __shared__ ushort Blds[CT * ND];
  int tid = threadIdx.x, lane = tid & 63, wave = tid >> 6;
  int g = lane >> 4, cl = lane & 15;
  int rowstart = blockIdx.x * RT;
  int split = blockIdx.y;

  stage64(hs + (size_t)rowstart * ND, Alds, wave, lane);
  __syncthreads();
  short8 af[8];                          // wave's 16 rows, K=256 hoisted: 32 VGPRs
#pragma unroll
  for (int kk = 0; kk < 8; ++kk) af[kk] = fload(Alds, wave * 16 + cl, kk * 4 + g);

  float s[4] = {0.f, 0.f, 0.f, 0.f};
  for (int it = 0; it < NITER; ++it) {
    int jbase = split * COLS_PER_SPLIT + it * CT;
    __syncthreads();                     // Blds readers of iter-1 done
    stage64(hs + (size_t)jbase * ND, Blds, wave, lane);
    __syncthreads();                     // Blds staged (vmcnt drained by barrier)

    f32x4 acc[4];
#pragma unroll
    for (int f = 0; f < 4; ++f) acc[f] = (f32x4){0.f, 0.f, 0.f, 0.f};
#pragma unroll
    for (int kk = 0; kk < 8; ++kk) {
      short8 b0 = fload(Blds, 0 * 16 + cl, kk * 4 + g);
      short8 b1 = fload(Blds, 1 * 16 + cl, kk * 4 + g);
      short8 b2 = fload(Blds, 2 * 16 + cl, kk * 4 + g);
      short8 b3 = fload(Blds, 3 * 16 + cl, kk * 4 + g);
      acc[0] = __builtin_amdgcn_mfma_f32_16x16x32_bf16(af[kk], b0, acc[0], 0, 0, 0);
      acc[1] = __builtin_amdgcn_mfma_f32_16x16x32_bf16(af[kk], b1, acc[1], 0, 0, 0);
      acc[2] = __builtin_amdgcn_mfma_f32_16x16x32_bf16(af[kk], b2, acc[2], 0, 0, 0);
      acc[3] = __builtin_amdgcn_mfma_f32_16x16x32_bf16(af[kk], b3, acc[3], 0, 0, 0);
    }
#pragma unroll
    for (int q = 0; q < 4; ++q)
      s[q] += __builtin_amdgcn_exp2f(acc[0][q]) + __builtin_amdgcn_exp2f(acc[1][q]) +
              __builtin_amdgcn_exp2f(acc[2][q]) + __builtin_amdgcn_exp2f(acc[3][q]);
  }

#pragma unroll
  for (int q = 0; q < 4; ++q) {
    float v = s[q];
#pragma unroll
    for (int d = 1; d <= 8; d <<= 1) v += __shfl_xor(v, d);
    if (cl == 0)
      partials[(size_t)split * NB + rowstart + wave * 16 + g * 4 + q] = v;
  }
}

// ------- per-row loss: Sp from class sums, denom from partials ---------------
__global__ void rowloss_kernel(const ushort* __restrict__ hs,
                               const int* __restrict__ labels,
                               const float* __restrict__ Cs,
                               const float* __restrict__ cnt,
                               const float* __restrict__ partials,
                               const float* __restrict__ dbuf,
                               float2* __restrict__ rl) {
  int lane = threadIdx.x & 63, wave = threadIdx.x >> 6;
  int row = blockIdx.x * 4 + wave;
  int lbl = labels[row];
  ushort4 qb = reinterpret_cast<const ushort4*>(hs + (size_t)row * ND)[lane];
  float4 cv = reinterpret_cast<const float4*>(Cs + (size_t)lbl * ND)[lane];
  float dot = bf2f(qb.x) * cv.x + bf2f(qb.y) * cv.y +
              bf2f(qb.z) * cv.z + bf2f(qb.w) * cv.w;
#pragma unroll
  for (int d = 1; d <= 32; d <<= 1) dot += __shfl_xor(dot, d);
  if (lane == 0) {
    float dself = dbuf[row];
    float sfull = partials[row] + partials[NB + row] +
                  partials[2 * NB + row] + partials[3 * NB + row];
    float s = sfull - (1.0f - 1e-8f) * __builtin_amdgcn_exp2f(dself);
    float denom2 = log2f(s);
    float Sp2 = dot - dself;             // sum over same-class, excluding self
    float n = cnt[lbl] - 1.0f;
    float li = 0.f, val = 0.f;
    if (n > 0.5f) { li = -LN2f * (Sp2 - n * denom2) / n; val = 1.f; }
    rl[row] = make_float2(li, val);
  }
}

__global__ void reduce_kernel(const float2* __restrict__ rl, float* __restrict__ out) {
  int t = threadIdx.x;
  float L = 0.f, V = 0.f;
  for (int r = t; r < NB; r += 256) { float2 p = rl[r]; L += p.x; V += p.y; }
#pragma unroll
  for (int d = 1; d <= 32; d <<= 1) { L += __shfl_xor(L, d); V += __shfl_xor(V, d); }
  __shared__ float sL[4], sV[4];
  if ((t & 63) == 0) { sL[t >> 6] = L; sV[t >> 6] = V; }
  __syncthreads();
  if (t == 0)
    out[0] = (sL[0] + sL[1] + sL[2] + sL[3]) /
             fmaxf(sV[0] + sV[1] + sV[2] + sV[3], 1.f);
}

extern "C" void kernel_launch(void* const* d_in, const int* in_sizes, int n_in,
                              void* d_out, int out_size, void* d_ws, size_t ws_size,
                              hipStream_t stream) {
  const float* hidden = (const float*)d_in[0];
  const int* labels = (const int*)d_in[1];
  float* out = (float*)d_out;

  ushort* hs      = (ushort*)d_ws;                            // 4,194,304 B
  float* dbuf     = (float*)((char*)d_ws + 4194304);          //    32,768 B
  float* Cs       = (float*)((char*)d_ws + 4227072);          //   102,400 B
  float* cnt      = (float*)((char*)d_ws + 4329472);          //       512 B
  float* partials = (float*)((char*)d_ws + 4329984);          //   131,072 B
  float2* rl      = (float2*)((char*)d_ws + 4461056);         //    65,536 B

  norm_kernel<<<NB / 4, 256, 0, stream>>>(hidden, hs, dbuf);
  classsum_kernel<<<100, 256, 0, stream>>>(hs, labels, Cs, cnt);
  denom_kernel<<<dim3(NB / RT, CS), 256, 0, stream>>>(hs, partials);
  rowloss_kernel<<<NB / 4, 256, 0, stream>>>(hs, labels, Cs, cnt, partials, dbuf, rl);
  reduce_kernel<<<1, 256, 0, stream>>>(rl, out);
}

// Round 3
// 71.984 us; speedup vs baseline: 1.1600x; 1.1600x over previous
//
#include <hip/hip_runtime.h>
#include <hip/hip_bf16.h>
#include <math.h>

typedef __attribute__((ext_vector_type(8))) short short8;
typedef __attribute__((ext_vector_type(4))) float f32x4;

#define NB 8192
#define ND 256
#define CS 16                       // column splits
#define CT 64                       // columns per iteration
#define NITER (NB / CS / CT)        // 8
#define TILE_USH 16384              // 64 rows * 256 cols ushort per K-major tile
#define LN2f 0.6931471805599453f

__device__ __forceinline__ float bf2f(ushort u) {
  unsigned int x = ((unsigned int)u) << 16;
  return __builtin_bit_cast(float, x);
}
__device__ __forceinline__ ushort f2bf(float x) {
  return __builtin_bit_cast(ushort, __float2bfloat16(x));
}

// ------- row normalize, fold 1/sqrt(T*ln2), quantize bf16, exact self d_r ----
__global__ void norm_kernel(const float* __restrict__ h, ushort* __restrict__ hs,
                            float* __restrict__ dbuf) {
  const float SCALE = 1.0f / sqrtf(0.07f * 0.6931471805599453f);
  int lane = threadIdx.x & 63;
  int wave = threadIdx.x >> 6;
  int row = blockIdx.x * 4 + wave;
  const float4* rp = reinterpret_cast<const float4*>(h + (size_t)row * ND);
  float4 v = rp[lane];
  float ss = v.x * v.x + v.y * v.y + v.z * v.z + v.w * v.w;
#pragma unroll
  for (int d = 1; d <= 32; d <<= 1) ss += __shfl_xor(ss, d);
  float scale = SCALE / fmaxf(sqrtf(ss), 1e-12f);
  ushort4 o;
  o.x = f2bf(v.x * scale);
  o.y = f2bf(v.y * scale);
  o.z = f2bf(v.z * scale);
  o.w = f2bf(v.w * scale);
  reinterpret_cast<ushort4*>(hs + (size_t)row * ND)[lane] = o;
  float qx = bf2f(o.x), qy = bf2f(o.y), qz = bf2f(o.z), qw = bf2f(o.w);
  float dd = qx * qx + qy * qy + qz * qz + qw * qw;   // exact ||q||^2 (log2 units)
#pragma unroll
  for (int d = 1; d <= 32; d <<= 1) dd += __shfl_xor(dd, d);
  if (lane == 0) dbuf[row] = dd;
}

// ------- hs [8192][256] -> K-major tiles hsK[jt][unit0..31][row0..63] (16B) ---
__global__ void transpose_kernel(const ushort* __restrict__ hs,
                                 ushort* __restrict__ hsK) {
  int jt = blockIdx.x;           // 128 tiles of 64 rows
  int t = threadIdx.x;
#pragma unroll
  for (int k = 0; k < 8; ++k) {
    int S = k * 256 + t;         // 16B slot in tile, 0..2047
    int u = S >> 6, r = S & 63;
    *(short8*)(hsK + (size_t)jt * TILE_USH + S * 8) =
        *(const short8*)(hs + ((size_t)jt * 64 + r) * ND + u * 8);
  }
}

// ------- per-class sums C_l = sum of quantized rows, and member counts -------
__global__ void classsum_kernel(const ushort* __restrict__ hs,
                                const int* __restrict__ labels,
                                float* __restrict__ Cs, float* __restrict__ cnt) {
  __shared__ int list[NB];
  __shared__ int lcnt;
  int c = blockIdx.x, t = threadIdx.x;
  if (t == 0) lcnt = 0;
  __syncthreads();
  for (int i = t; i < NB; i += 256)
    if (labels[i] == c) list[atomicAdd(&lcnt, 1)] = i;
  __syncthreads();
  int n = lcnt;
  float acc = 0.f;
  for (int k = 0; k < n; ++k)
    acc += bf2f(hs[(size_t)list[k] * ND + t]);
  Cs[c * ND + t] = acc;
  if (t == 0) cnt[c] = (float)n;
}

// stage one 64-col K-major tile (32KB) into LDS: pure linear copy
__device__ __forceinline__ void stageB(ushort* lds, const ushort* gsrc,
                                       int wave, int lane) {
#pragma unroll
  for (int c = 0; c < 8; ++c) {
    int base = (wave * 8 + c) * 512;             // ushort idx of 1KB chunk
    __builtin_amdgcn_global_load_lds(
        (const __attribute__((address_space(1))) unsigned int*)(gsrc + base + lane * 8),
        (__attribute__((address_space(3))) unsigned int*)(lds + base),
        16, 0, 0);
  }
}

// ------- denominator: s_r(split) = sum_j exp2(sim2_rj) -----------------------
__global__ __launch_bounds__(256, 2)
void denom_kernel(const ushort* __restrict__ hsK, float* __restrict__ partials) {
  __shared__ ushort Blds[2][CT * ND];            // 2 x 32KB
  int tid = threadIdx.x, lane = tid & 63, wave = tid >> 6;
  int g = lane >> 4, cl = lane & 15;

  // bijective XCD swizzle: 512 blocks, 8 XCDs -> cluster splits per XCD
  int id = blockIdx.x;
  int nid = (id & 7) * 64 + (id >> 3);
  int split = nid >> 5;                          // 0..15
  int rowblk = nid & 31;                         // 0..31

  // A fragments: this wave's 64 rows x K=256, from K-major tile, in registers
  const ushort* At = hsK + (size_t)(rowblk * 4 + wave) * TILE_USH;
  short8 af[4][8];
#pragma unroll
  for (int rf = 0; rf < 4; ++rf)
#pragma unroll
    for (int kk = 0; kk < 8; ++kk)
      af[rf][kk] = *(const short8*)(At + ((kk * 4 + g) * 64 + rf * 16 + cl) * 8);

  float s[16];
#pragma unroll
  for (int i = 0; i < 16; ++i) s[i] = 0.f;

  const ushort* Bbase = hsK + (size_t)(split * NITER) * TILE_USH;
  stageB(Blds[0], Bbase, wave, lane);
  __syncthreads();

  for (int it = 0; it < NITER; ++it) {
    if (it + 1 < NITER)
      stageB(Blds[(it + 1) & 1], Bbase + (size_t)(it + 1) * TILE_USH, wave, lane);
    const ushort* Bt = Blds[it & 1];

#pragma unroll
    for (int cf = 0; cf < 4; ++cf) {
      short8 bf[8];
#pragma unroll
      for (int kk = 0; kk < 8; ++kk)
        bf[kk] = *(const short8*)(Bt + ((kk * 4 + g) * 64 + cf * 16 + cl) * 8);
      f32x4 acc[4];
#pragma unroll
      for (int rf = 0; rf < 4; ++rf) acc[rf] = (f32x4){0.f, 0.f, 0.f, 0.f};
#pragma unroll
      for (int kk = 0; kk < 8; ++kk) {
#pragma unroll
        for (int rf = 0; rf < 4; ++rf)
          acc[rf] = __builtin_amdgcn_mfma_f32_16x16x32_bf16(af[rf][kk], bf[kk],
                                                            acc[rf], 0, 0, 0);
      }
#pragma unroll
      for (int rf = 0; rf < 4; ++rf)
#pragma unroll
        for (int q = 0; q < 4; ++q)
          s[rf * 4 + q] += __builtin_amdgcn_exp2f(acc[rf][q]);
    }
    __syncthreads();   // drains this iter's prefetch (vmcnt) + protects Blds
  }

  // fold lane-partials across the 16-lane column group
#pragma unroll
  for (int i = 0; i < 16; ++i) {
#pragma unroll
    for (int d = 1; d <= 8; d <<= 1) s[i] += __shfl_xor(s[i], d);
  }
  if (cl == 0) {
    int R0 = rowblk * 256 + wave * 64;
#pragma unroll
    for (int rf = 0; rf < 4; ++rf)
#pragma unroll
      for (int q = 0; q < 4; ++q)
        partials[(size_t)split * NB + R0 + rf * 16 + g * 4 + q] = s[rf * 4 + q];
  }
}

// ------- per-row loss: Sp from class sums, denom from partials ---------------
__global__ void rowloss_kernel(const ushort* __restrict__ hs,
                               const int* __restrict__ labels,
                               const float* __restrict__ Cs,
                               const float* __restrict__ cnt,
                               const float* __restrict__ partials,
                               const float* __restrict__ dbuf,
                               float2* __restrict__ rl) {
  int lane = threadIdx.x & 63, wave = threadIdx.x >> 6;
  int row = blockIdx.x * 4 + wave;
  int lbl = labels[row];
  ushort4 qb = reinterpret_cast<const ushort4*>(hs + (size_t)row * ND)[lane];
  float4 cv = reinterpret_cast<const float4*>(Cs + (size_t)lbl * ND)[lane];
  float dot = bf2f(qb.x) * cv.x + bf2f(qb.y) * cv.y +
              bf2f(qb.z) * cv.z + bf2f(qb.w) * cv.w;
#pragma unroll
  for (int d = 1; d <= 32; d <<= 1) dot += __shfl_xor(dot, d);
  if (lane == 0) {
    float dself = dbuf[row];
    float sfull = 0.f;
#pragma unroll
    for (int k = 0; k < CS; ++k) sfull += partials[(size_t)k * NB + row];
    float s = sfull - (1.0f - 1e-8f) * __builtin_amdgcn_exp2f(dself);
    float denom2 = log2f(s);
    float Sp2 = dot - dself;             // sum over same-class, excluding self
    float n = cnt[lbl] - 1.0f;
    float li = 0.f, val = 0.f;
    if (n > 0.5f) { li = -LN2f * (Sp2 - n * denom2) / n; val = 1.f; }
    rl[row] = make_float2(li, val);
  }
}

__global__ void reduce_kernel(const float2* __restrict__ rl, float* __restrict__ out) {
  int t = threadIdx.x;
  float L = 0.f, V = 0.f;
  for (int r = t; r < NB; r += 256) { float2 p = rl[r]; L += p.x; V += p.y; }
#pragma unroll
  for (int d = 1; d <= 32; d <<= 1) { L += __shfl_xor(L, d); V += __shfl_xor(V, d); }
  __shared__ float sL[4], sV[4];
  if ((t & 63) == 0) { sL[t >> 6] = L; sV[t >> 6] = V; }
  __syncthreads();
  if (t == 0)
    out[0] = (sL[0] + sL[1] + sL[2] + sL[3]) /
             fmaxf(sV[0] + sV[1] + sV[2] + sV[3], 1.f);
}

extern "C" void kernel_launch(void* const* d_in, const int* in_sizes, int n_in,
                              void* d_out, int out_size, void* d_ws, size_t ws_size,
                              hipStream_t stream) {
  const float* hidden = (const float*)d_in[0];
  const int* labels = (const int*)d_in[1];
  float* out = (float*)d_out;

  ushort* hs      = (ushort*)d_ws;                            // [0, 4MB)
  ushort* hsK     = (ushort*)((char*)d_ws + 4194304);         // [4MB, 8MB)
  float* dbuf     = (float*)((char*)d_ws + 8388608);          // 32KB
  float* Cs       = (float*)((char*)d_ws + 8421376);          // 100KB
  float* cnt      = (float*)((char*)d_ws + 8523776);          // 512B
  float* partials = (float*)((char*)d_ws + 8524288);          // 512KB
  float2* rl      = (float2*)((char*)d_ws + 9048576);         // 64KB

  norm_kernel<<<NB / 4, 256, 0, stream>>>(hidden, hs, dbuf);
  transpose_kernel<<<NB / 64, 256, 0, stream>>>(hs, hsK);
  classsum_kernel<<<100, 256, 0, stream>>>(hs, labels, Cs, cnt);
  denom_kernel<<<512, 256, 0, stream>>>(hsK, partials);
  rowloss_kernel<<<NB / 4, 256, 0, stream>>>(hs, labels, Cs, cnt, partials, dbuf, rl);
  reduce_kernel<<<1, 256, 0, stream>>>(rl, out);
}